// Round 10
// baseline (183.575 us; speedup 1.0000x reference)
//
#include <hip/hip_runtime.h>

// out[b,o,n] = sum_{i,k} x[b,i,4n+k] * w[o,i,4n+k] / sqrt(128)
// x: (64,128,4096) f32, w: (128,128,4096) f32, out: (64,128,1024) f32.
//
// Round-10: r6 verbatim + NON-TEMPORAL input loads (the one untested knob).
// Evidence r1-r9: input-read rate pinned at 2.3-2.5 TB/s across all load
// mechanisms/granules/occupancies; L3 serves ~half the reads (replay thrash
// of 384 MB inputs vs 256 MB L3). Theory: the mixed L3-hit/HBM-miss path is
// the limiter; `nt` streams inputs from HBM without L3 pollution/probing.
// A/B vs r6: only the GLD macro changed (adds `nt`).

#define CIN  128
#define COUT 128
#define ODIM 1024
#define DDIM 4096
#define CI   8
#define NCH  16
#define RS   512                         // shorts per LDS row
#define R4B  (4u * CIN * DDIM * 4u)      // +4 rows, bytes (8 MiB)
#define CHB  ((unsigned)(CI * DDIM * 4)) // +1 i-chunk, bytes (128 KiB)

typedef short bf16x8 __attribute__((ext_vector_type(8)));
typedef short s16x4  __attribute__((ext_vector_type(4)));
typedef float f32x4  __attribute__((ext_vector_type(4)));

static __device__ __forceinline__ unsigned short f2bf(float f) {
    unsigned int u = __float_as_uint(f);
    u += 0x7fffu + ((u >> 16) & 1u);   // RNE fp32 -> bf16
    return (unsigned short)(u >> 16);
}
static __device__ __forceinline__ s16x4 cvt4(float4 v) {
    s16x4 s;
    s[0] = (short)f2bf(v.x); s[1] = (short)f2bf(v.y);
    s[2] = (short)f2bf(v.z); s[3] = (short)f2bf(v.w);
    return s;
}

__global__ __launch_bounds__(512, 4)
void nolc_kernel(const float* __restrict__ xg,
                 const float* __restrict__ wg,
                 float* __restrict__ outg) {
    __shared__ short lds[64 * RS];   // 64 KB: rows 0-31 x(b), 32-63 w(o)

    const int bid  = blockIdx.x;
    const int gidx = (bid & 7) * 64 + (bid >> 3);   // XCD-contiguous
    const int ng   = gidx >> 3;                      // 0..63 (16 n each)
    const int bq   = (gidx >> 2) & 1;
    const int oq   = gidx & 3;

    const int t    = threadIdx.x;
    const int lane = t & 63;
    const int wave = t >> 6;

    // staging decomposition (16B unit): sn(n) x si(i) x rl(row low)
    const int sn = t & 15;
    const int si = (t >> 4) & 7;
    const int rl = t >> 7;          // 0..3

    const unsigned xoff =
        ((unsigned)((bq * 32 + rl) * CIN + si) * DDIM + (unsigned)(ng * 64 + sn * 4)) * 4u;
    const unsigned woff =
        ((unsigned)((oq * 32 + rl) * CIN + si) * DDIM + (unsigned)(ng * 64 + sn * 4)) * 4u;

    // compute decomposition: 8 waves = 2bt x 2ot x 2nh
    const int bt  = wave & 1;
    const int ot  = (wave >> 1) & 1;
    const int nh  = wave >> 2;
    const int r16 = lane & 15;
    const int kg  = lane >> 4;

    f32x4 acc[8];
#pragma unroll
    for (int n = 0; n < 8; ++n) acc[n] = (f32x4){0.f, 0.f, 0.f, 0.f};

    float4 fx0, fx1, fx2, fx3, fx4, fx5, fx6, fx7;
    float4 fw0, fw1, fw2, fw3, fw4, fw5, fw6, fw7;

    // NON-TEMPORAL: bypass cache retention on the streaming inputs
#define GLD(dst, off, base) \
    asm volatile("global_load_dwordx4 %0, %1, %2 nt" : "=v"(dst) : "v"(off), "s"(base))

#define ISSUE_X(c) do { unsigned _o = xoff + (unsigned)(c) * CHB;            \
    GLD(fx0, _o,           xg); GLD(fx1, _o + 1u*R4B, xg);                   \
    GLD(fx2, _o + 2u*R4B,  xg); GLD(fx3, _o + 3u*R4B, xg);                   \
    GLD(fx4, _o + 4u*R4B,  xg); GLD(fx5, _o + 5u*R4B, xg);                   \
    GLD(fx6, _o + 6u*R4B,  xg); GLD(fx7, _o + 7u*R4B, xg); } while (0)

#define ISSUE_W(c) do { unsigned _o = woff + (unsigned)(c) * CHB;            \
    GLD(fw0, _o,           wg); GLD(fw1, _o + 1u*R4B, wg);                   \
    GLD(fw2, _o + 2u*R4B,  wg); GLD(fw3, _o + 3u*R4B, wg);                   \
    GLD(fw4, _o + 4u*R4B,  wg); GLD(fw5, _o + 5u*R4B, wg);                   \
    GLD(fw6, _o + 6u*R4B,  wg); GLD(fw7, _o + 7u*R4B, wg); } while (0)

    // LDS addr (shorts): row*RS + si*64 + ((sn ^ (row&15))<<2)
#define STROW(v, it, rbase) do {                                             \
    const int _row = (rbase) + (it) * 4 + rl;                                \
    *reinterpret_cast<s16x4*>(                                               \
        &lds[_row * RS + si * 64 + ((sn ^ (_row & 15)) << 2)]) = cvt4(v);    \
    } while (0)

#define STX() do { STROW(fx0,0,0); STROW(fx1,1,0); STROW(fx2,2,0); STROW(fx3,3,0); \
                   STROW(fx4,4,0); STROW(fx5,5,0); STROW(fx6,6,0); STROW(fx7,7,0); } while (0)
#define STW() do { STROW(fw0,0,32); STROW(fw1,1,32); STROW(fw2,2,32); STROW(fw3,3,32); \
                   STROW(fw4,4,32); STROW(fw5,5,32); STROW(fw6,6,32); STROW(fw7,7,32); } while (0)

#define VMW8() do { asm volatile("s_waitcnt vmcnt(8)" ::: "memory");         \
                    __builtin_amdgcn_sched_barrier(0); } while (0)
#define VMW0() do { asm volatile("s_waitcnt vmcnt(0)" ::: "memory");         \
                    __builtin_amdgcn_sched_barrier(0); } while (0)

    const int xbase = (bt * 16 + r16) * RS;
    const int wbase = (32 + ot * 16 + r16) * RS;

    ISSUE_X(0);
    ISSUE_W(0);

#pragma unroll 1
    for (int c = 0; c < NCH; ++c) {
        VMW8();                          // x(c) done (w(c) still outstanding)
        STX();
        if (c + 1 < NCH) ISSUE_X(c + 1); // outstanding: w(c) 8 + x(c+1) 8

        if (c + 1 < NCH) { VMW8(); }     // w(c) done, x(c+1) in flight
        else             { VMW0(); }
        STW();
        if (c + 1 < NCH) ISSUE_W(c + 1);

        asm volatile("s_waitcnt lgkmcnt(0)" ::: "memory");
        __builtin_amdgcn_sched_barrier(0);
        __builtin_amdgcn_s_barrier();

#pragma unroll
        for (int nn = 0; nn < 8; ++nn) {
            const int n  = nh * 8 + nn;
            const int so = (n ^ r16) << 2;
            s16x4 a0 = *reinterpret_cast<const s16x4*>(&lds[xbase + (kg * 2) * 64 + so]);
            s16x4 a1 = *reinterpret_cast<const s16x4*>(&lds[xbase + (kg * 2 + 1) * 64 + so]);
            s16x4 b0 = *reinterpret_cast<const s16x4*>(&lds[wbase + (kg * 2) * 64 + so]);
            s16x4 b1 = *reinterpret_cast<const s16x4*>(&lds[wbase + (kg * 2 + 1) * 64 + so]);
            bf16x8 A = __builtin_shufflevector(a0, a1, 0, 1, 2, 3, 4, 5, 6, 7);
            bf16x8 B = __builtin_shufflevector(b0, b1, 0, 1, 2, 3, 4, 5, 6, 7);
            acc[nn] = __builtin_amdgcn_mfma_f32_16x16x32_bf16(A, B, acc[nn], 0, 0, 0);
        }
        if (c + 1 < NCH) __builtin_amdgcn_s_barrier();   // LDS reuse guard
    }

    // epilogue: col = o-local (lane&15), row = b-local (kg*4+reg)
    const float scale = 0.08838834764831845f;  // 1/sqrt(128)
    const int o = oq * 32 + ot * 16 + r16;
#pragma unroll
    for (int r = 0; r < 4; ++r) {
        const int b = bq * 32 + bt * 16 + kg * 4 + r;
        float* op = outg + ((size_t)b * COUT + o) * ODIM + ng * 16 + nh * 8;
        float4 v0, v1;
        v0.x = acc[0][r] * scale; v0.y = acc[1][r] * scale;
        v0.z = acc[2][r] * scale; v0.w = acc[3][r] * scale;
        v1.x = acc[4][r] * scale; v1.y = acc[5][r] * scale;
        v1.z = acc[6][r] * scale; v1.w = acc[7][r] * scale;
        *reinterpret_cast<float4*>(op)     = v0;
        *reinterpret_cast<float4*>(op + 4) = v1;
    }
}

extern "C" void kernel_launch(void* const* d_in, const int* in_sizes, int n_in,
                              void* d_out, int out_size, void* d_ws, size_t ws_size,
                              hipStream_t stream) {
    const float* x = (const float*)d_in[0];
    const float* w = (const float*)d_in[1];
    float* out = (float*)d_out;
    nolc_kernel<<<dim3(512), dim3(512), 0, stream>>>(x, w, out);
}

// Round 11
// 132.761 us; speedup vs baseline: 1.3827x; 1.3827x over previous
//
#include <hip/hip_runtime.h>

// out[b,o,n] = sum_{i,k} x[b,i,4n+k] * w[o,i,4n+k] / sqrt(128)
// x: (64,128,4096) f32 (128 MB), w: (128,128,4096) f32 (256 MB).
//
// Round-11: r6 verbatim + ASYMMETRIC cache policy.
//   Evidence: HBM-sourced reads concurrency-capped at ~2.4-2.8 TB/s
//   (r1-r10, all mechanisms); L3-sourced ~2x faster (gemm2). r10 (nt on
//   both) -> FETCH 365MB, 182us. r6 (cached both, thrashing mix) -> 275MB,
//   164us. Here: x stays cached (128MB fits the 256MB L3 across graph
//   replays), w streams `nt` (evict-first, stops w evicting x).
//   Steady state: x ~L3-hit, only w's 256MB pays the HBM wall.

#define CIN  128
#define COUT 128
#define ODIM 1024
#define DDIM 4096
#define CI   8
#define NCH  16
#define RS   512                         // shorts per LDS row
#define R4B  (4u * CIN * DDIM * 4u)      // +4 rows, bytes (8 MiB)
#define CHB  ((unsigned)(CI * DDIM * 4)) // +1 i-chunk, bytes (128 KiB)

typedef short bf16x8 __attribute__((ext_vector_type(8)));
typedef short s16x4  __attribute__((ext_vector_type(4)));
typedef float f32x4  __attribute__((ext_vector_type(4)));

static __device__ __forceinline__ unsigned short f2bf(float f) {
    unsigned int u = __float_as_uint(f);
    u += 0x7fffu + ((u >> 16) & 1u);   // RNE fp32 -> bf16
    return (unsigned short)(u >> 16);
}
static __device__ __forceinline__ s16x4 cvt4(float4 v) {
    s16x4 s;
    s[0] = (short)f2bf(v.x); s[1] = (short)f2bf(v.y);
    s[2] = (short)f2bf(v.z); s[3] = (short)f2bf(v.w);
    return s;
}

__global__ __launch_bounds__(512, 4)
void nolc_kernel(const float* __restrict__ xg,
                 const float* __restrict__ wg,
                 float* __restrict__ outg) {
    __shared__ short lds[64 * RS];   // 64 KB: rows 0-31 x(b), 32-63 w(o)

    const int bid  = blockIdx.x;
    const int gidx = (bid & 7) * 64 + (bid >> 3);   // XCD-contiguous
    const int ng   = gidx >> 3;                      // 0..63 (16 n each)
    const int bq   = (gidx >> 2) & 1;
    const int oq   = gidx & 3;

    const int t    = threadIdx.x;
    const int lane = t & 63;
    const int wave = t >> 6;

    // staging decomposition (16B unit): sn(n) x si(i) x rl(row low)
    const int sn = t & 15;
    const int si = (t >> 4) & 7;
    const int rl = t >> 7;          // 0..3

    const unsigned xoff =
        ((unsigned)((bq * 32 + rl) * CIN + si) * DDIM + (unsigned)(ng * 64 + sn * 4)) * 4u;
    const unsigned woff =
        ((unsigned)((oq * 32 + rl) * CIN + si) * DDIM + (unsigned)(ng * 64 + sn * 4)) * 4u;

    // compute decomposition: 8 waves = 2bt x 2ot x 2nh
    const int bt  = wave & 1;
    const int ot  = (wave >> 1) & 1;
    const int nh  = wave >> 2;
    const int r16 = lane & 15;
    const int kg  = lane >> 4;

    f32x4 acc[8];
#pragma unroll
    for (int n = 0; n < 8; ++n) acc[n] = (f32x4){0.f, 0.f, 0.f, 0.f};

    float4 fx0, fx1, fx2, fx3, fx4, fx5, fx6, fx7;
    float4 fw0, fw1, fw2, fw3, fw4, fw5, fw6, fw7;

    // x: cached (stays L3-resident across replays; 128MB < 256MB L3)
#define GLDC(dst, off, base) \
    asm volatile("global_load_dwordx4 %0, %1, %2" : "=v"(dst) : "v"(off), "s"(base))
    // w: non-temporal stream (evict-first; must not displace x in L3)
#define GLDNT(dst, off, base) \
    asm volatile("global_load_dwordx4 %0, %1, %2 nt" : "=v"(dst) : "v"(off), "s"(base))

#define ISSUE_X(c) do { unsigned _o = xoff + (unsigned)(c) * CHB;            \
    GLDC(fx0, _o,           xg); GLDC(fx1, _o + 1u*R4B, xg);                 \
    GLDC(fx2, _o + 2u*R4B,  xg); GLDC(fx3, _o + 3u*R4B, xg);                 \
    GLDC(fx4, _o + 4u*R4B,  xg); GLDC(fx5, _o + 5u*R4B, xg);                 \
    GLDC(fx6, _o + 6u*R4B,  xg); GLDC(fx7, _o + 7u*R4B, xg); } while (0)

#define ISSUE_W(c) do { unsigned _o = woff + (unsigned)(c) * CHB;            \
    GLDNT(fw0, _o,           wg); GLDNT(fw1, _o + 1u*R4B, wg);               \
    GLDNT(fw2, _o + 2u*R4B,  wg); GLDNT(fw3, _o + 3u*R4B, wg);               \
    GLDNT(fw4, _o + 4u*R4B,  wg); GLDNT(fw5, _o + 5u*R4B, wg);               \
    GLDNT(fw6, _o + 6u*R4B,  wg); GLDNT(fw7, _o + 7u*R4B, wg); } while (0)

    // LDS addr (shorts): row*RS + si*64 + ((sn ^ (row&15))<<2)
#define STROW(v, it, rbase) do {                                             \
    const int _row = (rbase) + (it) * 4 + rl;                                \
    *reinterpret_cast<s16x4*>(                                               \
        &lds[_row * RS + si * 64 + ((sn ^ (_row & 15)) << 2)]) = cvt4(v);    \
    } while (0)

#define STX() do { STROW(fx0,0,0); STROW(fx1,1,0); STROW(fx2,2,0); STROW(fx3,3,0); \
                   STROW(fx4,4,0); STROW(fx5,5,0); STROW(fx6,6,0); STROW(fx7,7,0); } while (0)
#define STW() do { STROW(fw0,0,32); STROW(fw1,1,32); STROW(fw2,2,32); STROW(fw3,3,32); \
                   STROW(fw4,4,32); STROW(fw5,5,32); STROW(fw6,6,32); STROW(fw7,7,32); } while (0)

#define VMW8() do { asm volatile("s_waitcnt vmcnt(8)" ::: "memory");         \
                    __builtin_amdgcn_sched_barrier(0); } while (0)
#define VMW0() do { asm volatile("s_waitcnt vmcnt(0)" ::: "memory");         \
                    __builtin_amdgcn_sched_barrier(0); } while (0)

    const int xbase = (bt * 16 + r16) * RS;
    const int wbase = (32 + ot * 16 + r16) * RS;

    ISSUE_X(0);
    ISSUE_W(0);

#pragma unroll 1
    for (int c = 0; c < NCH; ++c) {
        VMW8();                          // x(c) done (w(c) still outstanding)
        STX();
        if (c + 1 < NCH) ISSUE_X(c + 1); // outstanding: w(c) 8 + x(c+1) 8

        if (c + 1 < NCH) { VMW8(); }     // w(c) done, x(c+1) in flight
        else             { VMW0(); }
        STW();
        if (c + 1 < NCH) ISSUE_W(c + 1);

        asm volatile("s_waitcnt lgkmcnt(0)" ::: "memory");
        __builtin_amdgcn_sched_barrier(0);
        __builtin_amdgcn_s_barrier();

#pragma unroll
        for (int nn = 0; nn < 8; ++nn) {
            const int n  = nh * 8 + nn;
            const int so = (n ^ r16) << 2;
            s16x4 a0 = *reinterpret_cast<const s16x4*>(&lds[xbase + (kg * 2) * 64 + so]);
            s16x4 a1 = *reinterpret_cast<const s16x4*>(&lds[xbase + (kg * 2 + 1) * 64 + so]);
            s16x4 b0 = *reinterpret_cast<const s16x4*>(&lds[wbase + (kg * 2) * 64 + so]);
            s16x4 b1 = *reinterpret_cast<const s16x4*>(&lds[wbase + (kg * 2 + 1) * 64 + so]);
            bf16x8 A = __builtin_shufflevector(a0, a1, 0, 1, 2, 3, 4, 5, 6, 7);
            bf16x8 B = __builtin_shufflevector(b0, b1, 0, 1, 2, 3, 4, 5, 6, 7);
            acc[nn] = __builtin_amdgcn_mfma_f32_16x16x32_bf16(A, B, acc[nn], 0, 0, 0);
        }
        if (c + 1 < NCH) __builtin_amdgcn_s_barrier();   // LDS reuse guard
    }

    // epilogue: col = o-local (lane&15), row = b-local (kg*4+reg)
    const float scale = 0.08838834764831845f;  // 1/sqrt(128)
    const int o = oq * 32 + ot * 16 + r16;
#pragma unroll
    for (int r = 0; r < 4; ++r) {
        const int b = bq * 32 + bt * 16 + kg * 4 + r;
        float* op = outg + ((size_t)b * COUT + o) * ODIM + ng * 16 + nh * 8;
        float4 v0, v1;
        v0.x = acc[0][r] * scale; v0.y = acc[1][r] * scale;
        v0.z = acc[2][r] * scale; v0.w = acc[3][r] * scale;
        v1.x = acc[4][r] * scale; v1.y = acc[5][r] * scale;
        v1.z = acc[6][r] * scale; v1.w = acc[7][r] * scale;
        *reinterpret_cast<float4*>(op)     = v0;
        *reinterpret_cast<float4*>(op + 4) = v1;
    }
}

extern "C" void kernel_launch(void* const* d_in, const int* in_sizes, int n_in,
                              void* d_out, int out_size, void* d_ws, size_t ws_size,
                              hipStream_t stream) {
    const float* x = (const float*)d_in[0];
    const float* w = (const float*)d_in[1];
    float* out = (float*)d_out;
    nolc_kernel<<<dim3(512), dim3(512), 0, stream>>>(x, w, out);
}